// Round 1
// baseline (570.982 us; speedup 1.0000x reference)
//
#include <hip/hip_runtime.h>
#include <hip/hip_bf16.h>

// B=1024, n_el=32, n_up=16, n_ion=8, d_one=256, d_two=32, d_ion=64, d_elion=32, emb=64
// feats: (B,32,928); el_el_mult: (B,32,32,64)
// feats cols: [0:256 h_one][256:512 tile_up][512:768 tile_dn][768:800 f_pairs_up]
//             [800:832 f_pairs_dn][832:896 el_el][896:928 el_ion]

#define FEATS_ELEMS 30408704ull
#define FD 928

typedef __attribute__((ext_vector_type(8))) short bfrag8;   // 8 bf16 = 4 VGPR
typedef __attribute__((ext_vector_type(4))) float vf4;
typedef __attribute__((ext_vector_type(4))) unsigned short us4;

static __device__ __forceinline__ unsigned short f2bf(float f) {
    unsigned int u = __builtin_bit_cast(unsigned int, f);
    unsigned int r = (u + 0x7FFFu + ((u >> 16) & 1u)) >> 16;   // RNE, finite inputs
    return (unsigned short)r;
}
static __device__ __forceinline__ float bf2f(unsigned short u) {
    unsigned int v = ((unsigned int)u) << 16;
    return __builtin_bit_cast(float, v);
}
// tanh(x) = 1 - 2/(e^{2x}+1); exp->inf => 1, exp->0 => -1 (branchless, correct asymptotes)
static __device__ __forceinline__ float fast_tanh(float x) {
    float e = __expf(2.f * x);
    return 1.f - 2.f * __builtin_amdgcn_rcpf(e + 1.f);
}

// ---------------- Kernel 0: one-time weight convert to bf16, transposed [n][k] -----
// WhT: (64,256)  WsT: (64,32)  WdT: (64,32)
__global__ __launch_bounds__(256) void sf_prep(
    const float* __restrict__ W_hmap,   // (256,64)
    const float* __restrict__ W_wsame,  // (32,64)
    const float* __restrict__ W_wdiff,  // (32,64)
    unsigned short* __restrict__ WhT,
    unsigned short* __restrict__ WsT,
    unsigned short* __restrict__ WdT)
{
    int e = blockIdx.x * 256 + threadIdx.x;
    if (e < 16384) {
        int n = e >> 8, k = e & 255;
        WhT[e] = f2bf(W_hmap[k * 64 + n]);
    } else if (e < 18432) {
        int q = e - 16384;
        WsT[q] = f2bf(W_wsame[(q & 31) * 64 + (q >> 5)]);
    } else if (e < 20480) {
        int q = e - 18432;
        WdT[q] = f2bf(W_wdiff[(q & 31) * 64 + (q >> 5)]);
    }
}

// ---------------- Kernel 1: h_one feats + h_mapped (MFMA) + h_ion_mapped ----------
__global__ __launch_bounds__(256) void sf_k1(
    const float* __restrict__ h_one,          // (B,32,256)
    const float* __restrict__ h_ion,          // (B,8,64)
    const unsigned short* __restrict__ WhT,   // (64,256) bf16
    const float* __restrict__ b_hmap,         // (64)
    const float* __restrict__ W_ion,          // (64,32)
    const float* __restrict__ b_ion,          // (32)
    float* __restrict__ feats,
    float* __restrict__ hmap_ws,              // (B,32,64)
    float* __restrict__ hion_ws)              // (B,8,32)
{
    __shared__ unsigned short s_hbf[32 * 264];   // h_one as bf16, padded stride 264
    __shared__ vf4 s_part[4][64];                // partial col sums per row-group
    const int b = blockIdx.x;
    const int t = threadIdx.x;
    const int cg = t & 63;        // 4-column group: cols 4cg..4cg+3
    const int rg = t >> 6;        // 8-row group: rows 8rg..8rg+7

    // phase 1: vectorized copy h_one -> feats, bf16 stage, partial column sums
    const float* hb = h_one + (size_t)b * 8192;
    vf4 acc = {0.f, 0.f, 0.f, 0.f};
    #pragma unroll
    for (int r8 = 0; r8 < 8; ++r8) {
        const int row = rg * 8 + r8;
        vf4 v = ((const vf4*)hb)[row * 64 + cg];
        acc = acc + v;
        us4 w = { f2bf(v[0]), f2bf(v[1]), f2bf(v[2]), f2bf(v[3]) };
        *(us4*)(s_hbf + row * 264 + cg * 4) = w;
        *(vf4*)(feats + (size_t)(b * 32 + row) * FD + cg * 4) = v;
    }
    s_part[rg][cg] = acc;

    // h_ion_mapped (no LDS dependence, hide before barrier)
    {
        const int ai = t >> 5, kk = t & 31;
        float d = b_ion[kk];
        const float* hi = h_ion + (size_t)b * 512 + ai * 64;
        #pragma unroll 8
        for (int k2 = 0; k2 < 64; ++k2) d += hi[k2] * W_ion[k2 * 32 + kk];
        hion_ws[(size_t)b * 256 + ai * 32 + kk] = fast_tanh(d);
    }
    __syncthreads();

    // tile_up / tile_dn, vectorized
    {
        vf4 su = (s_part[0][cg] + s_part[1][cg]) * (1.f / 16.f);
        vf4 sd = (s_part[2][cg] + s_part[3][cg]) * (1.f / 16.f);
        #pragma unroll
        for (int r8 = 0; r8 < 8; ++r8) {
            const int row = rg * 8 + r8;
            size_t base = (size_t)(b * 32 + row) * FD;
            *(vf4*)(feats + base + 256 + cg * 4) = su;
            *(vf4*)(feats + base + 512 + cg * 4) = sd;
        }
    }

    // phase 2: h_mapped = tanh(h_one @ W_hmap + b) via mfma 16x16x32 bf16
    const int lane  = t & 63;
    const int nt    = t >> 6;        // wave -> 16-col tile
    const int col15 = lane & 15;
    const int quad  = lane >> 4;
    const int col   = nt * 16 + col15;

    float bh = b_hmap[col];
    vf4 acc0 = {bh, bh, bh, bh};     // rows 0..15
    vf4 acc1 = acc0;                 // rows 16..31
    #pragma unroll
    for (int ks = 0; ks < 8; ++ks) {
        const bfrag8 bf = *(const bfrag8*)(WhT + col * 256 + ks * 32 + quad * 8);
        const bfrag8 a0 = *(const bfrag8*)(s_hbf + col15 * 264 + ks * 32 + quad * 8);
        const bfrag8 a1 = *(const bfrag8*)(s_hbf + (16 + col15) * 264 + ks * 32 + quad * 8);
        acc0 = __builtin_amdgcn_mfma_f32_16x16x32_bf16(a0, bf, acc0, 0, 0, 0);
        acc1 = __builtin_amdgcn_mfma_f32_16x16x32_bf16(a1, bf, acc1, 0, 0, 0);
    }
    #pragma unroll
    for (int r = 0; r < 4; ++r) {
        int j0 = quad * 4 + r;       // C/D: row = quad*4+reg, col = lane&15
        hmap_ws[(size_t)(b * 32 + j0) * 64 + col]      = fast_tanh(acc0[r]);
        hmap_ws[(size_t)(b * 32 + 16 + j0) * 64 + col] = fast_tanh(acc1[r]);
    }
}

// ---------------- Kernel 2: mult + el_el + f_pairs + el_ion (MFMA) ----------------
// grid = B*8 blocks; wave wv handles electron i = i0 + wv. No h_el_el LDS staging:
// A-fragments load straight from global (per-lane addr == MFMA A layout).
__global__ __launch_bounds__(256) void sf_k2(
    const float* __restrict__ h_el_el,        // (B,32,32,32)
    const float* __restrict__ h_el_ion,       // (B,32,8,32)
    const unsigned short* __restrict__ WsT,   // (64,32) bf16
    const unsigned short* __restrict__ WdT,   // (64,32) bf16
    const float* __restrict__ b_wsame,        // (64)
    const float* __restrict__ b_wdiff,        // (64)
    const float* __restrict__ hmap_ws,        // (B,32,64)
    const float* __restrict__ hion_ws,        // (B,8,32)
    float* __restrict__ feats,
    float* __restrict__ mult_out)             // (B,32,32,64)
{
    __shared__ float s_hmap[32 * 68];          // 32 j x 64 e fp32, stride 68
    const int b  = blockIdx.x >> 3;
    const int i0 = (blockIdx.x & 7) * 4;
    const int t  = threadIdx.x;
    const int lane  = t & 63;
    const int wv    = t >> 6;
    const int i     = i0 + wv;
    const int col15 = lane & 15;
    const int quad  = lane >> 4;

    // stage hmap (fp32, vectorized)
    {
        const float* hm = hmap_ws + (size_t)b * 2048;
        #pragma unroll
        for (int r = 0; r < 2; ++r) {
            int c = r * 256 + t;
            vf4 v = ((const vf4*)hm)[c];
            int g = 4 * c;
            *(vf4*)(s_hmap + (g >> 6) * 68 + (g & 63)) = v;
        }
    }

    // A-fragments direct from global: row j = col15 (+16), k = quad*8..quad*8+7
    const float* hrow = h_el_el + (size_t)(b * 32 + i) * 1024;
    const int ub = col15 * 8 + quad * 2;          // vf4 index of (j=col15, k=quad*8)
    const int db = (16 + col15) * 8 + quad * 2;
    vf4 u0 = ((const vf4*)hrow)[ub];
    vf4 u1 = ((const vf4*)hrow)[ub + 1];
    vf4 d0 = ((const vf4*)hrow)[db];
    vf4 d1 = ((const vf4*)hrow)[db + 1];
    bfrag8 a_up, a_dn;
    #pragma unroll
    for (int ii = 0; ii < 4; ++ii) {
        a_up[ii]     = (short)f2bf(u0[ii]);
        a_up[ii + 4] = (short)f2bf(u1[ii]);
        a_dn[ii]     = (short)f2bf(d0[ii]);
        a_dn[ii + 4] = (short)f2bf(d1[ii]);
    }

    // B-fragments: single 16B vector loads from pre-converted bf16 weights
    bfrag8 bs_fr[4], bd_fr[4];
    #pragma unroll
    for (int nt = 0; nt < 4; ++nt) {
        const int n = nt * 16 + col15;
        bs_fr[nt] = *(const bfrag8*)(WsT + n * 32 + quad * 8);
        bd_fr[nt] = *(const bfrag8*)(WdT + n * 32 + quad * 8);
    }
    __syncthreads();

    const bool iup = (i < 16);
    float* mrow = mult_out + (size_t)(b * 32 + i) * 2048;
    const size_t frow = (size_t)(b * 32 + i) * FD;

    #pragma unroll
    for (int nt = 0; nt < 4; ++nt) {
        const int col = nt * 16 + col15;
        float vbs = b_wsame[col], vbd = b_wdiff[col];
        float bu = iup ? vbs : vbd;
        float bd = iup ? vbd : vbs;
        bfrag8 fu = iup ? bs_fr[nt] : bd_fr[nt];   // j<16 rows weight
        bfrag8 fd = iup ? bd_fr[nt] : bs_fr[nt];   // j>=16 rows weight
        vf4 cu = {bu, bu, bu, bu};
        vf4 cd = {bd, bd, bd, bd};
        cu = __builtin_amdgcn_mfma_f32_16x16x32_bf16(a_up, fu, cu, 0, 0, 0);
        cd = __builtin_amdgcn_mfma_f32_16x16x32_bf16(a_dn, fd, cd, 0, 0, 0);
        float s = 0.f;
        #pragma unroll
        for (int r = 0; r < 4; ++r) {
            int ju = quad * 4 + r;
            float mu = fast_tanh(cu[r]) * s_hmap[ju * 68 + col];
            mrow[ju * 64 + col] = mu;
            int jd = 16 + ju;
            float md = fast_tanh(cd[r]) * s_hmap[jd * 68 + col];
            mrow[jd * 64 + col] = md;
            s += mu + md;
        }
        s += __shfl_xor(s, 16, 64);
        s += __shfl_xor(s, 32, 64);
        if (quad == 0) feats[frow + 832 + col] = s * (1.f / 16.f);
    }

    // f_pairs from the A-fragments: reduce over j (= col15 lanes, lane bits 0..3)
    {
        float vU[8], vD[8];
        #pragma unroll
        for (int ii = 0; ii < 8; ++ii) {
            vU[ii] = bf2f((unsigned short)a_up[ii]);
            vD[ii] = bf2f((unsigned short)a_dn[ii]);
        }
        #pragma unroll
        for (int m = 1; m <= 8; m <<= 1) {
            #pragma unroll
            for (int ii = 0; ii < 8; ++ii) {
                vU[ii] += __shfl_xor(vU[ii], m, 64);
                vD[ii] += __shfl_xor(vD[ii], m, 64);
            }
        }
        if (col15 == 0) {
            #pragma unroll
            for (int ii = 0; ii < 8; ++ii) {
                feats[frow + 768 + quad * 8 + ii] = vU[ii] * (1.f / 16.f);
                feats[frow + 800 + quad * 8 + ii] = vD[ii] * (1.f / 16.f);
            }
        }
    }

    // el_ion
    if (lane < 32) {
        const float* hei = h_el_ion + (size_t)(b * 32 + i) * 256;
        const float* him = hion_ws + (size_t)b * 256;
        float s = 0.f;
        #pragma unroll
        for (int a = 0; a < 8; ++a) s += hei[a * 32 + lane] * him[a * 32 + lane];
        feats[frow + 896 + lane] = s * (1.f / 8.f);
    }
}

extern "C" void kernel_launch(void* const* d_in, const int* in_sizes, int n_in,
                              void* d_out, int out_size, void* d_ws, size_t ws_size,
                              hipStream_t stream) {
    const float* h_one    = (const float*)d_in[0];
    const float* h_ion    = (const float*)d_in[1];
    const float* h_el_el  = (const float*)d_in[2];
    const float* h_el_ion = (const float*)d_in[3];
    const float* W_hmap   = (const float*)d_in[4];
    const float* b_hmap   = (const float*)d_in[5];
    const float* W_wsame  = (const float*)d_in[6];
    const float* b_wsame  = (const float*)d_in[7];
    const float* W_wdiff  = (const float*)d_in[8];
    const float* b_wdiff  = (const float*)d_in[9];
    const float* W_ion    = (const float*)d_in[10];
    const float* b_ion    = (const float*)d_in[11];

    float* feats    = (float*)d_out;
    float* mult_out = feats + FEATS_ELEMS;

    float* hmap_ws = (float*)d_ws;                       // 1024*32*64 floats
    float* hion_ws = hmap_ws + 1024 * 32 * 64;           // 1024*8*32 floats
    unsigned short* WhT = (unsigned short*)(hion_ws + 1024 * 8 * 32);  // 16384 bf16
    unsigned short* WsT = WhT + 16384;                   // 2048 bf16
    unsigned short* WdT = WsT + 2048;                    // 2048 bf16

    sf_prep<<<80, 256, 0, stream>>>(W_hmap, W_wsame, W_wdiff, WhT, WsT, WdT);
    sf_k1<<<1024, 256, 0, stream>>>(h_one, h_ion, WhT, b_hmap, W_ion, b_ion,
                                    feats, hmap_ws, hion_ws);
    sf_k2<<<1024 * 8, 256, 0, stream>>>(h_el_el, h_el_ion, WsT, WdT,
                                        b_wsame, b_wdiff, hmap_ws, hion_ws,
                                        feats, mult_out);
}